// Round 12
// baseline (376.445 us; speedup 1.0000x reference)
//
#include <hip/hip_runtime.h>

typedef __attribute__((ext_vector_type(8))) short short8;
typedef __attribute__((ext_vector_type(4))) float f32x4;
typedef __attribute__((ext_vector_type(4))) unsigned short us4;

#define L_SEQ 2048
#define C_DIM 512
#define H_N 8
#define D_H 64
#define FF_DIM 2048

typedef __attribute__((address_space(3))) unsigned int as3_uint;
typedef const __attribute__((address_space(1))) unsigned int as1_uint;

__device__ __forceinline__ void gl16(const unsigned short* g, unsigned short* l) {
  __builtin_amdgcn_global_load_lds((as1_uint*)g, (as3_uint*)l, 16, 0, 0);
}

__device__ __forceinline__ unsigned short f2bf(float f) {
  unsigned int u = __float_as_uint(f);
  u = u + 0x7fffu + ((u >> 16) & 1u);
  return (unsigned short)(u >> 16);
}

__device__ __forceinline__ unsigned int cvtpk_bf16(float a, float b) {
  unsigned int r;
  asm("v_cvt_pk_bf16_f32 %0, %1, %2" : "=v"(r) : "v"(a), "v"(b));
  return r;  // lo = bf16(a), hi = bf16(b)
}

// ---------- transpose + fp32->bf16 convert: out[J(n)][k] = in[k][n] ----------
__global__ __launch_bounds__(256) void transpose_conv(
    const float* __restrict__ in, unsigned short* __restrict__ out,
    int R, int Ccols, int geglu) {
  __shared__ float tile[32][33];
  int tx = threadIdx.x & 31, ty = threadIdx.x >> 5;
  int c0 = blockIdx.x * 32, r0 = blockIdx.y * 32;
#pragma unroll
  for (int j = 0; j < 4; ++j) {
    int r = ty + j * 8;
    tile[r][tx] = in[(size_t)(r0 + r) * Ccols + c0 + tx];
  }
  __syncthreads();
#pragma unroll
  for (int j = 0; j < 4; ++j) {
    int rr = ty + j * 8;
    int n = c0 + rr;
    int J = n;
    if (geglu) {
      int hc = Ccols >> 1;
      J = (n < hc) ? (((n >> 4) << 5) + (n & 15))
                   : ((((n - hc) >> 4) << 5) + 16 + ((n - hc) & 15));
    }
    out[(size_t)J * R + r0 + tx] = f2bf(tile[tx][rr]);
  }
}

// ---------- LayerNorm fp32 -> bf16 (one wave per row, C=512) ----------
__global__ __launch_bounds__(256) void ln_kernel(
    const float* __restrict__ in, const float* __restrict__ g,
    const float* __restrict__ b, unsigned short* __restrict__ out) {
  int w = threadIdx.x >> 6, lane = threadIdx.x & 63;
  int row = blockIdx.x * 4 + w;
  const float4* p = (const float4*)(in + (size_t)row * C_DIM);
  float4 v0 = p[lane * 2], v1 = p[lane * 2 + 1];
  float s = v0.x + v0.y + v0.z + v0.w + v1.x + v1.y + v1.z + v1.w;
  float q = v0.x * v0.x + v0.y * v0.y + v0.z * v0.z + v0.w * v0.w +
            v1.x * v1.x + v1.y * v1.y + v1.z * v1.z + v1.w * v1.w;
#pragma unroll
  for (int m = 1; m < 64; m <<= 1) {
    s += __shfl_xor(s, m);
    q += __shfl_xor(q, m);
  }
  float mean = s * (1.0f / 512.0f);
  float var = q * (1.0f / 512.0f) - mean * mean;
  float rstd = rsqrtf(var + 1e-5f);
  const float4* gp = (const float4*)g;
  const float4* bp = (const float4*)b;
  float4 g0 = gp[lane * 2], g1 = gp[lane * 2 + 1];
  float4 b0 = bp[lane * 2], b1 = bp[lane * 2 + 1];
  short8 o;
  o[0] = (short)f2bf((v0.x - mean) * rstd * g0.x + b0.x);
  o[1] = (short)f2bf((v0.y - mean) * rstd * g0.y + b0.y);
  o[2] = (short)f2bf((v0.z - mean) * rstd * g0.z + b0.z);
  o[3] = (short)f2bf((v0.w - mean) * rstd * g0.w + b0.w);
  o[4] = (short)f2bf((v1.x - mean) * rstd * g1.x + b1.x);
  o[5] = (short)f2bf((v1.y - mean) * rstd * g1.y + b1.y);
  o[6] = (short)f2bf((v1.z - mean) * rstd * g1.z + b1.z);
  o[7] = (short)f2bf((v1.w - mean) * rstd * g1.w + b1.w);
  *((short8*)(out + (size_t)row * C_DIM) + lane) = o;
}

// ---------- GEMM: C[M,N] = A[M,K] @ Bt[N,K]^T (+epilogue), N-tile = TN ------
template <int EPI, int TN>
__global__ __launch_bounds__(256, 2) void gemm_kernel(
    const unsigned short* __restrict__ A, const unsigned short* __restrict__ Bt,
    int M, int N, int K,
    const float* __restrict__ bias0, const float* __restrict__ bias1,
    const float* __restrict__ bias2, const float* __restrict__ resid,
    void* __restrict__ outp) {
  constexpr int NW = TN / 2;   // wave N-span
  constexpr int NF = TN / 32;  // N frags per wave
  __shared__ unsigned short As[128 * 32];
  __shared__ unsigned short Bs[TN * 32];
  int tid = threadIdx.x;
  int lane = tid & 63, w = tid >> 6;
  int wr = w >> 1, wc = w & 1;
  int hi = lane >> 4, l15 = lane & 15;
  int m0 = blockIdx.y * 128, n0 = blockIdx.x * TN;

  f32x4 acc[4][NF];
#pragma unroll
  for (int i = 0; i < 4; ++i)
#pragma unroll
    for (int j = 0; j < NF; ++j) acc[i][j] = (f32x4){0.f, 0.f, 0.f, 0.f};

  int srow = w * 16 + (lane >> 2);
  int scol = (lane & 3) * 8;
  const unsigned short* aG0 = A + (size_t)(m0 + srow) * K + scol;
  const unsigned short* aG1 = A + (size_t)(m0 + 64 + srow) * K + scol;
  const unsigned short* bG0 = Bt + (size_t)(n0 + srow) * K + scol;
  const unsigned short* bG1 = Bt + (size_t)(n0 + 64 + srow) * K + scol;
  unsigned short* aL0 = &As[w * 512];
  unsigned short* aL1 = &As[2048 + w * 512];
  unsigned short* bL0 = &Bs[w * 512];
  unsigned short* bL1 = &Bs[2048 + w * 512];

  for (int k0 = 0; k0 < K; k0 += 32) {
    __syncthreads();
    gl16(aG0 + k0, aL0);
    gl16(aG1 + k0, aL1);
    gl16(bG0 + k0, bL0);
    if (TN == 128) gl16(bG1 + k0, bL1);
    __syncthreads();
    short8 af[4], bf[NF];
#pragma unroll
    for (int mi = 0; mi < 4; ++mi)
      af[mi] = *(const short8*)&As[(wr * 64 + mi * 16 + l15) * 32 + hi * 8];
#pragma unroll
    for (int ni = 0; ni < NF; ++ni)
      bf[ni] = *(const short8*)&Bs[(wc * NW + ni * 16 + l15) * 32 + hi * 8];
#pragma unroll
    for (int mi = 0; mi < 4; ++mi)
#pragma unroll
      for (int ni = 0; ni < NF; ++ni)
        acc[mi][ni] = __builtin_amdgcn_mfma_f32_16x16x32_bf16(
            af[mi], bf[ni], acc[mi][ni], 0, 0, 0);
  }

  if (EPI == 0) {
    unsigned short* out = (unsigned short*)outp;
#pragma unroll
    for (int mi = 0; mi < 4; ++mi) {
#pragma unroll
      for (int ni = 0; ni < NF; ++ni) {
        int col = n0 + wc * NW + ni * 16 + l15;
        int t = col >> 9, jj = col & 511;
        int h = jj >> 6, d = jj & 63;
        const float* bptr = (t == 0) ? bias0 : (t == 1 ? bias1 : bias2);
        float bv = bptr[jj];
        int rbase = m0 + wr * 64 + mi * 16 + hi * 4;
        if (t == 2) {
          us4 pk;
#pragma unroll
          for (int i = 0; i < 4; ++i) pk[i] = f2bf(acc[mi][ni][i] + bv);
          int n = rbase >> 11, l = rbase & 2047;
          size_t dst = 8388608u + ((size_t)((n * H_N + h) * D_H + d)) * L_SEQ + l;
          *(us4*)(out + dst) = pk;
        } else {
#pragma unroll
          for (int i = 0; i < 4; ++i) {
            int m = rbase + i;
            int n = m >> 11, l = m & 2047;
            float val = acc[mi][ni][i] + bv;
            if (t == 0) val *= 0.18033688011112042f;  // fold 0.125*log2e into Q
            size_t dst = (size_t)t * 4194304u +
                         (((size_t)(n * H_N + h)) * L_SEQ + l) * D_H + d;
            out[dst] = f2bf(val);
          }
        }
      }
    }
  } else if (EPI == 1) {
    unsigned short* out = (unsigned short*)outp;
#pragma unroll
    for (int mi = 0; mi < 4; ++mi) {
#pragma unroll
      for (int np = 0; np < 2; ++np) {
        int J16 = (n0 >> 4) + wc * 4 + np * 2;
        int ucol = (J16 >> 1) * 16 + l15;
        float bu = bias0[ucol], bg = bias0[2048 + ucol];
        int rbase = m0 + wr * 64 + mi * 16 + hi * 4;
#pragma unroll
        for (int i = 0; i < 4; ++i) {
          float uu = acc[mi][np * 2][i] + bu;
          float gg = acc[mi][np * 2 + 1][i] + bg;
          float ge = 0.5f * gg * (1.0f + erff(gg * 0.70710678118f));
          out[(size_t)(rbase + i) * FF_DIM + ucol] = f2bf(uu * ge);
        }
      }
    }
  } else {
    float* out = (float*)outp;
#pragma unroll
    for (int mi = 0; mi < 4; ++mi) {
#pragma unroll
      for (int ni = 0; ni < NF; ++ni) {
        int col = n0 + wc * NW + ni * 16 + l15;
        float bv = bias0[col];
        int rbase = m0 + wr * 64 + mi * 16 + hi * 4;
#pragma unroll
        for (int i = 0; i < 4; ++i) {
          size_t idx = (size_t)(rbase + i) * C_DIM + col;
          out[idx] = acc[mi][ni][i] + bv + resid[idx];
        }
      }
    }
  }
}

// ---------- flash attention: token-split, K in LDS, V direct from L2 --------
// Waves 0-3: tokens 0..1023; waves 4-7: tokens 1024..2047 (same 64 q-rows).
// No-max softmax => partials exactly additive. KVBLK=32.
// K rows 128B XOR-swizzled in LDS; V^T read straight from global (L2-resident).
__global__ __launch_bounds__(512, 6) void attn_kernel(
    const unsigned short* __restrict__ qkv, const float* __restrict__ x,
    float* __restrict__ x1) {
  // LDS map: [0,16K) K tiles (half*2+buf)*4KB ; [16K,26K) P per-wave 1280B.
  // Combine phase reuses [0,20480) after the final barrier.
  __shared__ __align__(16) char lds_raw[26624];

  int tid = threadIdx.x, lane = tid & 63, w = tid >> 6;  // w 0..7
  int half = w >> 2, wq = w & 3;
  int hi = lane >> 4, l15 = lane & 15;
  int bid = blockIdx.x;
  // XCD-bijective swizzle: XCD k owns heads 4k..4k+3 (K/V L2-resident)
  int k8 = bid & 7, j = bid >> 3;
  int nh = (k8 << 2) + (j & 3);
  int q0 = (j >> 2) << 6;  // 32 q-blocks of 64
  int n = nh >> 3, h = nh & 7;
  const unsigned short* qb = qkv + (size_t)nh * (L_SEQ * D_H);
  const unsigned short* kb = qb + 4194304u;
  const unsigned short* vtb = qkv + 8388608u + (size_t)nh * (D_H * L_SEQ);

  // Q B-frags: row=q(l15), k=d(m*32+hi*8+j)
  short8 qf[2];
#pragma unroll
  for (int m = 0; m < 2; ++m)
    qf[m] = *(const short8*)(qb + (size_t)(q0 + wq * 16 + l15) * D_H + m * 32 + hi * 8);

  f32x4 O[4];
#pragma unroll
  for (int c = 0; c < 4; ++c) O[c] = (f32x4){0.f, 0.f, 0.f, 0.f};
  float lsum = 0.f;

  const int T0 = half << 10;  // token base for this wave-group
  // K staging lane map (8 rows x 8 slots per wave-issue), inverse-swizzled src
  int kr = wq * 8 + (lane >> 3);
  int kc = (((lane & 7) ^ (lane >> 3)) << 3);

#define KBb(bb) ((unsigned short*)(lds_raw + (((half << 1) | (bb)) << 12)))
  unsigned int* plw = (unsigned int*)(lds_raw + 16384 + w * 1280);

#define STAGE(tt, bb)                                            \
  {                                                              \
    int t0s = T0 + (tt) * 32;                                    \
    gl16(kb + (size_t)(t0s + kr) * 64 + kc, KBb(bb) + wq * 512); \
  }

  STAGE(0, 0)
  int buf = 0;
  int swz = (l15 & 7) << 4;

  for (int t = 0; t < 32; ++t) {
    __syncthreads();  // drains vmcnt: current K tile staged; prev buf free
    if (t < 31) STAGE(t + 1, buf ^ 1)

    // --- V frags direct from global (L2): A=V^T rows=d, k=token ---
    const unsigned short* vg = vtb + T0 + t * 32 + hi * 8;
    short8 vf[4];
#pragma unroll
    for (int c = 0; c < 4; ++c)
      vf[c] = *(const short8*)(vg + (size_t)(c * 16 + l15) * 2048);

    // --- QK^T: A=K (rows=tokens), B=Q (cols=q) ---
    const char* Kbase = (const char*)KBb(buf);
    short8 kf[2][2];
#pragma unroll
    for (int mc = 0; mc < 2; ++mc)
#pragma unroll
      for (int m = 0; m < 2; ++m) {
        int off = (mc * 16 + l15) * 128 + ((m * 64 + hi * 16) ^ swz);
        kf[mc][m] = *(const short8*)(Kbase + off);
      }

    // --- P = exp2(S), packed bf16 to LDS; lane-local sum ---
#pragma unroll
    for (int mc = 0; mc < 2; ++mc) {
      f32x4 s = (f32x4){0.f, 0.f, 0.f, 0.f};
      s = __builtin_amdgcn_mfma_f32_16x16x32_bf16(kf[mc][0], qf[0], s, 0, 0, 0);
      s = __builtin_amdgcn_mfma_f32_16x16x32_bf16(kf[mc][1], qf[1], s, 0, 0, 0);
      float p0 = __builtin_amdgcn_exp2f(s[0]);
      float p1 = __builtin_amdgcn_exp2f(s[1]);
      float p2 = __builtin_amdgcn_exp2f(s[2]);
      float p3 = __builtin_amdgcn_exp2f(s[3]);
      lsum += (p0 + p1) + (p2 + p3);
      uint2 pw;
      pw.x = cvtpk_bf16(p0, p1);
      pw.y = cvtpk_bf16(p2, p3);
      *(uint2*)((char*)plw + (l15 * 20 + mc * 8 + hi * 2) * 4) = pw;
    }

    // --- PV: A=V^T (rows=d), B=P^T (cols=q), k=32 ---
    short8 pf = *(const short8*)((const char*)plw + l15 * 80 + hi * 16);
#pragma unroll
    for (int c = 0; c < 4; ++c)
      O[c] = __builtin_amdgcn_mfma_f32_16x16x32_bf16(vf[c], pf, O[c], 0, 0, 0);
    buf ^= 1;
  }

  // --- combine halves (exact: no-max softmax partials are additive) ---
  __syncthreads();
  float* cm = (float*)lds_raw;
  float* my = cm + (size_t)(wq * 64 + lane) * 20;
  if (half == 1) {
#pragma unroll
    for (int c = 0; c < 4; ++c) *(f32x4*)(my + c * 4) = O[c];
    my[16] = lsum;
  }
  __syncthreads();
  if (half == 0) {
#pragma unroll
    for (int c = 0; c < 4; ++c) {
      f32x4 ob = *(const f32x4*)(my + c * 4);
      O[c][0] += ob[0]; O[c][1] += ob[1]; O[c][2] += ob[2]; O[c][3] += ob[3];
    }
    lsum += my[16];
    lsum += __shfl_xor(lsum, 16);
    lsum += __shfl_xor(lsum, 32);
    float invl = 1.0f / lsum;

    int tok = q0 + wq * 16 + l15;
    size_t base = ((size_t)(n * L_SEQ + tok)) * C_DIM + h * 64;
#pragma unroll
    for (int c = 0; c < 4; ++c) {
      const float4 xv = *(const float4*)(x + base + c * 16 + hi * 4);
      float4 ov;
      ov.x = xv.x + O[c][0] * invl;
      ov.y = xv.y + O[c][1] * invl;
      ov.z = xv.z + O[c][2] * invl;
      ov.w = xv.w + O[c][3] * invl;
      *(float4*)(x1 + base + c * 16 + hi * 4) = ov;
    }
  }
#undef STAGE
#undef KBb
}

extern "C" void kernel_launch(void* const* d_in, const int* in_sizes, int n_in,
                              void* d_out, int out_size, void* d_ws,
                              size_t ws_size, hipStream_t stream) {
  const float* x = (const float*)d_in[0];
  const float* ln0g = (const float*)d_in[1];
  const float* ln0b = (const float*)d_in[2];
  const float* Wq = (const float*)d_in[3];
  const float* bq = (const float*)d_in[4];
  const float* Wk = (const float*)d_in[5];
  const float* bk = (const float*)d_in[6];
  const float* Wv = (const float*)d_in[7];
  const float* bv = (const float*)d_in[8];
  const float* ln1g = (const float*)d_in[9];
  const float* ln1b = (const float*)d_in[10];
  const float* Wp = (const float*)d_in[11];
  const float* bp = (const float*)d_in[12];
  const float* W2 = (const float*)d_in[13];
  const float* b2 = (const float*)d_in[14];

  char* ws = (char*)d_ws;
  unsigned short* hbuf = (unsigned short*)ws;                // 8192*512 bf16
  unsigned short* qkvb = (unsigned short*)(ws + 8388608);    // 3*4194304 bf16
  unsigned short* ybuf = (unsigned short*)ws;                // 8192*2048 bf16 (reuse)
  float* x1 = (float*)(ws + 33554432);                       // 8192*512 f32
  unsigned short* h2 = (unsigned short*)(ws + 33554432 + 16777216);
  unsigned short* wqkvt = (unsigned short*)(ws + 33554432 + 16777216 + 8388608);
  unsigned short* wpt = wqkvt + 1536 * 512;
  unsigned short* w2t = wpt + 4096 * 512;

  transpose_conv<<<dim3(16, 16), 256, 0, stream>>>(Wq, wqkvt, 512, 512, 0);
  transpose_conv<<<dim3(16, 16), 256, 0, stream>>>(Wk, wqkvt + 262144, 512, 512, 0);
  transpose_conv<<<dim3(16, 16), 256, 0, stream>>>(Wv, wqkvt + 524288, 512, 512, 0);
  transpose_conv<<<dim3(128, 16), 256, 0, stream>>>(Wp, wpt, 512, 4096, 1);
  transpose_conv<<<dim3(16, 64), 256, 0, stream>>>(W2, w2t, 2048, 512, 0);

  ln_kernel<<<2048, 256, 0, stream>>>(x, ln0g, ln0b, hbuf);
  gemm_kernel<0, 128><<<dim3(12, 64), 256, 0, stream>>>(
      hbuf, wqkvt, 8192, 1536, 512, bq, bk, bv, nullptr, qkvb);
  attn_kernel<<<1024, 512, 0, stream>>>(qkvb, x, x1);
  ln_kernel<<<2048, 256, 0, stream>>>(x1, ln1g, ln1b, h2);
  gemm_kernel<1, 128><<<dim3(32, 64), 256, 0, stream>>>(
      h2, wpt, 8192, 4096, 512, bp, nullptr, nullptr, nullptr, ybuf);
  gemm_kernel<2, 64><<<dim3(8, 64), 256, 0, stream>>>(
      ybuf, w2t, 8192, 512, 2048, b2, nullptr, nullptr, x1, (float*)d_out);
}